// Round 1
// baseline (13285.757 us; speedup 1.0000x reference)
//
#include <hip/hip_runtime.h>
#include <stdint.h>
#include <stddef.h>

typedef __attribute__((ext_vector_type(8))) short short8;
typedef __attribute__((ext_vector_type(4))) float f32x4;

#define MFMA16(A, B, C) __builtin_amdgcn_mfma_f32_16x16x32_bf16((A), (B), (C), 0, 0, 0)

// ---------- workspace layout (bytes) ----------
static const size_t OFF_XB   = 0;                    // x bf16      [64*512, 1024]  67108864
static const size_t OFF_WIH  = 67108864;             // w_ih bf16   [4096, 1024]     8388608
static const size_t OFF_WHH  = 75497472;             // w_hh bf16   [4096, 1024]     8388608
static const size_t OFF_BIAS = 83886080;             // b_ih+b_hh   [4096] f32         16384
static const size_t OFF_H0   = 83902464;             // h buf 0 bf16 [64,1024]        131072
static const size_t OFF_H1   = 84033536;             // h buf 1 bf16                  131072
static const size_t OFF_C    = 84164608;             // c f32 [64,1024]               262144
static const size_t OFF_XW   = 84426752;             // xW [512*64, 4096] f32 or bf16
static const size_t XW_F32_BYTES = 536870912;

__device__ __forceinline__ unsigned short f2bf(float f) {
    union { float f; uint32_t u; } v; v.f = f;
    uint32_t u = v.u;
    u += 0x7FFFu + ((u >> 16) & 1u);   // round-to-nearest-even
    return (unsigned short)(u >> 16);
}
__device__ __forceinline__ float bf2f(unsigned short b) {
    union { uint32_t u; float f; } v; v.u = ((uint32_t)b) << 16;
    return v.f;
}

// ---------- cast fp32 -> bf16, 4 elems/thread ----------
__global__ __launch_bounds__(256) void cast4_kernel(const float* __restrict__ s,
                                                    unsigned short* __restrict__ d, int n4) {
    int i = blockIdx.x * 256 + threadIdx.x;
    if (i >= n4) return;
    float4 f = ((const float4*)s)[i];
    ushort4 o;
    o.x = f2bf(f.x); o.y = f2bf(f.y); o.z = f2bf(f.z); o.w = f2bf(f.w);
    ((ushort4*)d)[i] = o;
}

// ---------- bias fold + state init ----------
__global__ __launch_bounds__(256) void init_misc(const float* __restrict__ b_ih,
                                                 const float* __restrict__ b_hh,
                                                 float* __restrict__ bias,
                                                 const float* __restrict__ h0,
                                                 const float* __restrict__ c0,
                                                 unsigned short* __restrict__ h_ini,
                                                 float* __restrict__ cbuf) {
    int i = blockIdx.x * 256 + threadIdx.x;
    if (i < 4096) bias[i] = b_ih[i] + b_hh[i];
    if (i < 65536) {
        h_ini[i] = f2bf(h0[i]);
        cbuf[i]  = c0[i];
    }
}

// ---------- xW GEMM: C[t*64+b][g] = sum_k x[b*512+t][k] * w_ih[g][k] + bias[g] ----------
// M=32768, N=4096, K=1024. 128x128 tile, BK=32, 4 waves (each 64x64 = 4x4 frags).
template <bool XWF32>
__global__ __launch_bounds__(256) void xw_gemm(const unsigned short* __restrict__ xb,
                                               const unsigned short* __restrict__ wb,
                                               const float* __restrict__ bias,
                                               void* __restrict__ xw) {
    __shared__ __align__(16) unsigned short As[128 * 32];
    __shared__ __align__(16) unsigned short Bs[128 * 32];
    const int bm = blockIdx.x, bn = blockIdx.y;
    const int tid = threadIdx.x;
    const int wave = tid >> 6, lane = tid & 63;
    const int wm = (wave >> 1) * 64, wn = (wave & 1) * 64;
    const int lr = lane & 15, lk = (lane >> 4) * 8;

    // staging map: 512 chunks of 8 bf16 per tile; thread handles chunks tid, tid+256
    const int c0 = tid, c1 = tid + 256;
    const int r0 = c0 >> 2, k0c = (c0 & 3) * 8;
    const int r1 = c1 >> 2, k1c = (c1 & 3) * 8;
    const int mA0 = bm * 128 + r0, mA1 = bm * 128 + r1;
    // output row m = t*64+b  ->  x row = b*512+t
    const unsigned short* pa0 = xb + (size_t)(((mA0 & 63) << 9) + (mA0 >> 6)) * 1024 + k0c;
    const unsigned short* pa1 = xb + (size_t)(((mA1 & 63) << 9) + (mA1 >> 6)) * 1024 + k1c;
    const unsigned short* pb0 = wb + (size_t)(bn * 128 + r0) * 1024 + k0c;
    const unsigned short* pb1 = wb + (size_t)(bn * 128 + r1) * 1024 + k1c;
    unsigned short* sa0 = As + r0 * 32 + k0c;
    unsigned short* sa1 = As + r1 * 32 + k1c;
    unsigned short* sb0 = Bs + r0 * 32 + k0c;
    unsigned short* sb1 = Bs + r1 * 32 + k1c;

    f32x4 acc[4][4] = {};

    for (int kk = 0; kk < 32; ++kk) {
        const int ko = kk * 32;
        uint4 av0 = *(const uint4*)(pa0 + ko);
        uint4 av1 = *(const uint4*)(pa1 + ko);
        uint4 bv0 = *(const uint4*)(pb0 + ko);
        uint4 bv1 = *(const uint4*)(pb1 + ko);
        __syncthreads();
        *(uint4*)sa0 = av0;
        *(uint4*)sa1 = av1;
        *(uint4*)sb0 = bv0;
        *(uint4*)sb1 = bv1;
        __syncthreads();
        short8 af[4], bfr[4];
#pragma unroll
        for (int mi = 0; mi < 4; ++mi)
            af[mi] = *(const short8*)(As + (wm + mi * 16 + lr) * 32 + lk);
#pragma unroll
        for (int ni = 0; ni < 4; ++ni)
            bfr[ni] = *(const short8*)(Bs + (wn + ni * 16 + lr) * 32 + lk);
#pragma unroll
        for (int mi = 0; mi < 4; ++mi)
#pragma unroll
            for (int ni = 0; ni < 4; ++ni)
                acc[mi][ni] = MFMA16(af[mi], bfr[ni], acc[mi][ni]);
    }

    const int rbase = (lane >> 4) * 4;
#pragma unroll
    for (int ni = 0; ni < 4; ++ni) {
        const int gc = bn * 128 + wn + ni * 16 + lr;
        const float bv = bias[gc];
#pragma unroll
        for (int mi = 0; mi < 4; ++mi) {
            const int gr = bm * 128 + wm + mi * 16 + rbase;
#pragma unroll
            for (int r = 0; r < 4; ++r) {
                float v = acc[mi][ni][r] + bv;
                if (XWF32) ((float*)xw)[(size_t)(gr + r) * 4096 + gc] = v;
                else ((unsigned short*)xw)[(size_t)(gr + r) * 4096 + gc] = f2bf(v);
            }
        }
    }
}

// ---------- one recurrence step ----------
// 64 blocks x 512 thr (8 waves). Block owns channels [bk*16, bk*16+16).
// Wave w: gate q = w&3, batch half mh = w>>2. lin = h_prev @ w_hh.T (MFMA), then gates fp32.
template <bool XWF32>
__global__ __launch_bounds__(512) void lstm_step(const unsigned short* __restrict__ hp,
                                                 unsigned short* __restrict__ hn,
                                                 float* __restrict__ c,
                                                 const void* __restrict__ xw,
                                                 const unsigned short* __restrict__ whh,
                                                 const float* __restrict__ fb,
                                                 float* __restrict__ out,
                                                 float* __restrict__ hcout,
                                                 int t) {
    __shared__ __align__(16) float lin[64][16][4];  // [batch][ch][gate]
    const int tid = threadIdx.x;
    const int wave = tid >> 6, lane = tid & 63;
    const int bk = blockIdx.x;
    const int ch0 = bk * 16;
    const int q = wave & 3, mh = wave >> 2;
    const int lr = lane & 15, lk = (lane >> 4) * 8;

    // prefetch epilogue operands early (independent of MFMA loop)
    float xwv[2][4], cold[2], fbv[2];
#pragma unroll
    for (int pp = 0; pp < 2; ++pp) {
        const int p = tid + pp * 512;
        const int b = p >> 4, j = p & 15, ch = ch0 + j;
        const size_t base = ((size_t)t * 64 + b) * 4096 + ch;
#pragma unroll
        for (int g = 0; g < 4; ++g)
            xwv[pp][g] = XWF32 ? ((const float*)xw)[base + g * 1024]
                               : bf2f(((const unsigned short*)xw)[base + g * 1024]);
        cold[pp] = c[b * 1024 + ch];
        fbv[pp]  = fb[ch];
    }

    // lin_q[batch][ch0+lr] over K=1024: M=32 (2 frags), N=16, direct-from-global frags
    f32x4 acc0 = {}, acc1 = {};
    const unsigned short* wrow = whh + (size_t)(q * 1024 + ch0 + lr) * 1024 + lk;
    const unsigned short* ha = hp + (size_t)(mh * 32 + lr) * 1024 + lk;
    const unsigned short* hb = hp + (size_t)(mh * 32 + 16 + lr) * 1024 + lk;
#pragma unroll 4
    for (int kc = 0; kc < 32; ++kc) {
        const int ko = kc * 32;
        short8 bv = *(const short8*)(wrow + ko);
        short8 a0 = *(const short8*)(ha + ko);
        short8 a1 = *(const short8*)(hb + ko);
        acc0 = MFMA16(a0, bv, acc0);
        acc1 = MFMA16(a1, bv, acc1);
    }

    const int rbase = (lane >> 4) * 4;
#pragma unroll
    for (int r = 0; r < 4; ++r) {
        lin[mh * 32 + rbase + r][lr][q]      = acc0[r];
        lin[mh * 32 + 16 + rbase + r][lr][q] = acc1[r];
    }
    __syncthreads();

#pragma unroll
    for (int pp = 0; pp < 2; ++pp) {
        const int p = tid + pp * 512;
        const int b = p >> 4, j = p & 15, ch = ch0 + j;
        const float4 l4 = *(const float4*)&lin[b][j][0];
        const float lr_ = l4.x + xwv[pp][0];
        const float lf  = l4.y + xwv[pp][1];
        const float lu  = l4.z + xwv[pp][2];
        const float lo  = l4.w + xwv[pp][3];
        const float fbx = fbv[pp];
        const float rg = 1.f / (1.f + expf(-(lr_ - fbx)));
        const float fg = 1.f / (1.f + expf(-(lf + fbx)));
        const float ug = tanhf(lu);
        const float og = 1.f / (1.f + expf(-lo));
        const float omf = 1.f - fg;
        const float gg = rg * (1.f - omf * omf) + (1.f - rg) * (fg * fg);
        const float cn = gg * cold[pp] + (1.f - gg) * ug;
        const float hnv = og * tanhf(cn);
        c[b * 1024 + ch] = cn;
        hn[b * 1024 + ch] = f2bf(hnv);
        out[((size_t)b * 512 + t) * 1024 + ch] = hnv;
        if (t == 511) {
            hcout[b * 1024 + ch] = hnv;           // h_n [1,64,1024]
            hcout[65536 + b * 1024 + ch] = cn;    // c_n [1,64,1024]
        }
    }
}

extern "C" void kernel_launch(void* const* d_in, const int* in_sizes, int n_in,
                              void* d_out, int out_size, void* d_ws, size_t ws_size,
                              hipStream_t stream) {
    const float* x   = (const float*)d_in[0];
    const float* wih = (const float*)d_in[1];
    const float* bih = (const float*)d_in[2];
    const float* whh = (const float*)d_in[3];
    const float* bhh = (const float*)d_in[4];
    const float* fb  = (const float*)d_in[5];
    const float* h0  = (const float*)d_in[6];
    const float* c0  = (const float*)d_in[7];

    char* ws = (char*)d_ws;
    float* out = (float*)d_out;
    float* hc  = out + 33554432;  // h_n, then c_n

    unsigned short* xb   = (unsigned short*)(ws + OFF_XB);
    unsigned short* wihb = (unsigned short*)(ws + OFF_WIH);
    unsigned short* whhb = (unsigned short*)(ws + OFF_WHH);
    float* bias          = (float*)(ws + OFF_BIAS);
    unsigned short* hb0  = (unsigned short*)(ws + OFF_H0);
    unsigned short* hb1  = (unsigned short*)(ws + OFF_H1);
    float* cbuf          = (float*)(ws + OFF_C);
    void* xw             = (void*)(ws + OFF_XW);

    const bool f32path = ws_size >= OFF_XW + XW_F32_BYTES;

    cast4_kernel<<<32768, 256, 0, stream>>>(x, xb, 8388608);
    cast4_kernel<<<4096, 256, 0, stream>>>(wih, wihb, 1048576);
    cast4_kernel<<<4096, 256, 0, stream>>>(whh, whhb, 1048576);
    init_misc<<<256, 256, 0, stream>>>(bih, bhh, bias, h0, c0, hb0, cbuf);

    dim3 g(256, 32);
    if (f32path) xw_gemm<true><<<g, 256, 0, stream>>>(xb, wihb, bias, xw);
    else         xw_gemm<false><<<g, 256, 0, stream>>>(xb, wihb, bias, xw);

    for (int t = 0; t < 512; ++t) {
        const unsigned short* hp = (t & 1) ? hb1 : hb0;
        unsigned short* hnx      = (t & 1) ? hb0 : hb1;
        if (f32path)
            lstm_step<true><<<64, 512, 0, stream>>>(hp, hnx, cbuf, xw, whhb, fb, out, hc, t);
        else
            lstm_step<false><<<64, 512, 0, stream>>>(hp, hnx, cbuf, xw, whhb, fb, out, hc, t);
    }
}

// Round 2
// 12170.804 us; speedup vs baseline: 1.0916x; 1.0916x over previous
//
#include <hip/hip_runtime.h>
#include <stdint.h>
#include <stddef.h>

typedef __attribute__((ext_vector_type(8))) short short8;
typedef __attribute__((ext_vector_type(4))) float f32x4;

#define MFMA16(A, B, C) __builtin_amdgcn_mfma_f32_16x16x32_bf16((A), (B), (C), 0, 0, 0)

// ---------- workspace layout (bytes) ----------
static const size_t OFF_XB   = 0;                    // x bf16      [64*512, 1024]  67108864
static const size_t OFF_WIH  = 67108864;             // w_ih bf16   [4096, 1024]     8388608
static const size_t OFF_WHH  = 75497472;             // w_hh bf16   [4096, 1024]     8388608
static const size_t OFF_BIAS = 83886080;             // b_ih+b_hh   [4096] f32         16384
static const size_t OFF_H0   = 83902464;             // h buf 0 bf16 [64,1024]        131072
static const size_t OFF_H1   = 84033536;             // h buf 1 bf16                  131072
static const size_t OFF_BAR  = 84164608;             // grid barrier counter (u32)
static const size_t OFF_XW   = 84426752;             // xW [512*64, 4096] f32 or bf16
static const size_t XW_F32_BYTES = 536870912;

__device__ __forceinline__ unsigned short f2bf(float f) {
    union { float f; uint32_t u; } v; v.f = f;
    uint32_t u = v.u;
    u += 0x7FFFu + ((u >> 16) & 1u);   // round-to-nearest-even
    return (unsigned short)(u >> 16);
}
__device__ __forceinline__ float bf2f(unsigned short b) {
    union { uint32_t u; float f; } v; v.u = ((uint32_t)b) << 16;
    return v.f;
}

// ---------- cast fp32 -> bf16, 4 elems/thread ----------
__global__ __launch_bounds__(256) void cast4_kernel(const float* __restrict__ s,
                                                    unsigned short* __restrict__ d, int n4) {
    int i = blockIdx.x * 256 + threadIdx.x;
    if (i >= n4) return;
    float4 f = ((const float4*)s)[i];
    ushort4 o;
    o.x = f2bf(f.x); o.y = f2bf(f.y); o.z = f2bf(f.z); o.w = f2bf(f.w);
    ((ushort4*)d)[i] = o;
}

// ---------- bias fold + h0 init + barrier zero ----------
__global__ __launch_bounds__(256) void init_misc(const float* __restrict__ b_ih,
                                                 const float* __restrict__ b_hh,
                                                 float* __restrict__ bias,
                                                 const float* __restrict__ h0,
                                                 unsigned short* __restrict__ h_ini,
                                                 unsigned int* __restrict__ bar) {
    int i = blockIdx.x * 256 + threadIdx.x;
    if (i == 0) *bar = 0u;
    if (i < 4096) bias[i] = b_ih[i] + b_hh[i];
    if (i < 65536) h_ini[i] = f2bf(h0[i]);
}

// ---------- xW GEMM: C[t*64+b][g] = sum_k x[b*512+t][k] * w_ih[g][k] + bias[g] ----------
// M=32768, N=4096, K=1024. 128x128 tile, BK=32, 4 waves (each 64x64 = 4x4 frags).
template <bool XWF32>
__global__ __launch_bounds__(256) void xw_gemm(const unsigned short* __restrict__ xb,
                                               const unsigned short* __restrict__ wb,
                                               const float* __restrict__ bias,
                                               void* __restrict__ xw) {
    __shared__ __align__(16) unsigned short As[128 * 32];
    __shared__ __align__(16) unsigned short Bs[128 * 32];
    const int bm = blockIdx.x, bn = blockIdx.y;
    const int tid = threadIdx.x;
    const int wave = tid >> 6, lane = tid & 63;
    const int wm = (wave >> 1) * 64, wn = (wave & 1) * 64;
    const int lr = lane & 15, lk = (lane >> 4) * 8;

    const int c0 = tid, c1 = tid + 256;
    const int r0 = c0 >> 2, k0c = (c0 & 3) * 8;
    const int r1 = c1 >> 2, k1c = (c1 & 3) * 8;
    const int mA0 = bm * 128 + r0, mA1 = bm * 128 + r1;
    const unsigned short* pa0 = xb + (size_t)(((mA0 & 63) << 9) + (mA0 >> 6)) * 1024 + k0c;
    const unsigned short* pa1 = xb + (size_t)(((mA1 & 63) << 9) + (mA1 >> 6)) * 1024 + k1c;
    const unsigned short* pb0 = wb + (size_t)(bn * 128 + r0) * 1024 + k0c;
    const unsigned short* pb1 = wb + (size_t)(bn * 128 + r1) * 1024 + k1c;
    unsigned short* sa0 = As + r0 * 32 + k0c;
    unsigned short* sa1 = As + r1 * 32 + k1c;
    unsigned short* sb0 = Bs + r0 * 32 + k0c;
    unsigned short* sb1 = Bs + r1 * 32 + k1c;

    f32x4 acc[4][4] = {};

    for (int kk = 0; kk < 32; ++kk) {
        const int ko = kk * 32;
        uint4 av0 = *(const uint4*)(pa0 + ko);
        uint4 av1 = *(const uint4*)(pa1 + ko);
        uint4 bv0 = *(const uint4*)(pb0 + ko);
        uint4 bv1 = *(const uint4*)(pb1 + ko);
        __syncthreads();
        *(uint4*)sa0 = av0;
        *(uint4*)sa1 = av1;
        *(uint4*)sb0 = bv0;
        *(uint4*)sb1 = bv1;
        __syncthreads();
        short8 af[4], bfr[4];
#pragma unroll
        for (int mi = 0; mi < 4; ++mi)
            af[mi] = *(const short8*)(As + (wm + mi * 16 + lr) * 32 + lk);
#pragma unroll
        for (int ni = 0; ni < 4; ++ni)
            bfr[ni] = *(const short8*)(Bs + (wn + ni * 16 + lr) * 32 + lk);
#pragma unroll
        for (int mi = 0; mi < 4; ++mi)
#pragma unroll
            for (int ni = 0; ni < 4; ++ni)
                acc[mi][ni] = MFMA16(af[mi], bfr[ni], acc[mi][ni]);
    }

    const int rbase = (lane >> 4) * 4;
#pragma unroll
    for (int ni = 0; ni < 4; ++ni) {
        const int gc = bn * 128 + wn + ni * 16 + lr;
        const float bv = bias[gc];
#pragma unroll
        for (int mi = 0; mi < 4; ++mi) {
            const int gr = bm * 128 + wm + mi * 16 + rbase;
#pragma unroll
            for (int r = 0; r < 4; ++r) {
                float v = acc[mi][ni][r] + bv;
                if (XWF32) ((float*)xw)[(size_t)(gr + r) * 4096 + gc] = v;
                else ((unsigned short*)xw)[(size_t)(gr + r) * 4096 + gc] = f2bf(v);
            }
        }
    }
}

// ---------- device-scope grid barrier (monotonic counter, cooperative launch) ----------
__device__ __forceinline__ void grid_barrier(unsigned int* bar, unsigned int target) {
    __threadfence();                       // release: my stores visible agent-wide
    __syncthreads();
    if (threadIdx.x == 0) {
        __hip_atomic_fetch_add(bar, 1u, __ATOMIC_RELAXED, __HIP_MEMORY_SCOPE_AGENT);
        while (__hip_atomic_load(bar, __ATOMIC_RELAXED, __HIP_MEMORY_SCOPE_AGENT) < target) {}
    }
    __syncthreads();
    __builtin_amdgcn_fence(__ATOMIC_ACQUIRE, "agent");   // invalidate L1 before re-reading h
}

// ---------- persistent recurrence: 64 blocks x 512 thr, all 512 steps in one launch ----------
// Block bk owns channels [bk*16, bk*16+16) x 4 gates = 64 rows of w_hh, held in REGISTERS:
// wave (mh = w>>2, kq = w&3): B-frags for all 64 N-rows x K-quarter kq -> 32 x short8 = 128 VGPR.
// Per step: h (bf16, global, double-buffered) read once per block as MFMA A-frags; K-partials
// reduced through LDS; gates fp32; c lives in per-thread registers for all 512 steps.
template <bool XWF32>
__global__ __launch_bounds__(512, 2) void lstm_persistent(
        unsigned short* hb0, unsigned short* hb1,
        const void* __restrict__ xw,
        const unsigned short* __restrict__ whh,
        const float* __restrict__ fb,
        const float* __restrict__ c0,
        float* __restrict__ out,
        float* __restrict__ hcout,
        unsigned int* bar) {
    const int tid = threadIdx.x;
    const int wave = tid >> 6, lane = tid & 63;
    const int bk = blockIdx.x, ch0 = bk * 16;
    const int mh = wave >> 2, kq = wave & 3;
    const int lr = lane & 15, lk = (lane >> 4) * 8, rbase = (lane >> 4) * 4;
    const int kqoff = kq * 256;

    __shared__ float part[4][64][64];   // [kq][batch][n=gate*16+ch]  64 KB

    // ---- preload W_hh fragments into registers (live for all 512 steps) ----
    short8 Bf[4][8];
#pragma unroll
    for (int ni = 0; ni < 4; ++ni) {
        const unsigned short* wrow = whh + (size_t)(ni * 1024 + ch0 + lr) * 1024 + kqoff + lk;
#pragma unroll
        for (int ks = 0; ks < 8; ++ks)
            Bf[ni][ks] = *(const short8*)(wrow + ks * 32);
    }

    // ---- per-thread epilogue constants: thread owns 2 (batch, channel) pairs ----
    int bb[2], jj[2];
    float fbv[2], creg[2];
#pragma unroll
    for (int pp = 0; pp < 2; ++pp) {
        const int p = tid + pp * 512;
        bb[pp] = p >> 4; jj[pp] = p & 15;
        const int ch = ch0 + jj[pp];
        fbv[pp]  = fb[ch];
        creg[pp] = c0[bb[pp] * 1024 + ch];
    }

    for (int t = 0; t < 512; ++t) {
        const unsigned short* hp = (t & 1) ? hb1 : hb0;
        unsigned short* hn       = (t & 1) ? hb0 : hb1;

        // prefetch xW slice for this step (consumed after the LDS barrier)
        float xwv[2][4];
#pragma unroll
        for (int pp = 0; pp < 2; ++pp) {
            const size_t base = ((size_t)t * 64 + bb[pp]) * 4096 + ch0 + jj[pp];
#pragma unroll
            for (int g = 0; g < 4; ++g)
                xwv[pp][g] = XWF32 ? ((const float*)xw)[base + g * 1024]
                                   : bf2f(((const unsigned short*)xw)[base + g * 1024]);
        }

        // ---- MFMA: lin_partial[b in mh-half][n] over K-quarter kq ----
        f32x4 acc[2][4] = {};
        const unsigned short* pa0 = hp + (size_t)(mh * 32 + lr) * 1024 + kqoff + lk;
        const unsigned short* pa1 = pa0 + 16 * 1024;
#pragma unroll
        for (int ks = 0; ks < 8; ++ks) {
            short8 a0 = *(const short8*)(pa0 + ks * 32);
            short8 a1 = *(const short8*)(pa1 + ks * 32);
#pragma unroll
            for (int ni = 0; ni < 4; ++ni) {
                acc[0][ni] = MFMA16(a0, Bf[ni][ks], acc[0][ni]);
                acc[1][ni] = MFMA16(a1, Bf[ni][ks], acc[1][ni]);
            }
        }

        // ---- write K-partials to LDS ----
#pragma unroll
        for (int mi = 0; mi < 2; ++mi)
#pragma unroll
            for (int ni = 0; ni < 4; ++ni)
#pragma unroll
                for (int r = 0; r < 4; ++r)
                    part[kq][mh * 32 + mi * 16 + rbase + r][ni * 16 + lr] = acc[mi][ni][r];
        __syncthreads();

        // ---- reduce K-partials + gates + state update ----
#pragma unroll
        for (int pp = 0; pp < 2; ++pp) {
            const int b = bb[pp], j = jj[pp], ch = ch0 + j;
            float l[4];
#pragma unroll
            for (int g = 0; g < 4; ++g)
                l[g] = part[0][b][g * 16 + j] + part[1][b][g * 16 + j]
                     + part[2][b][g * 16 + j] + part[3][b][g * 16 + j] + xwv[pp][g];
            const float fbx = fbv[pp];
            const float rg = 1.f / (1.f + expf(-(l[0] - fbx)));
            const float fg = 1.f / (1.f + expf(-(l[1] + fbx)));
            const float ug = tanhf(l[2]);
            const float og = 1.f / (1.f + expf(-l[3]));
            const float omf = 1.f - fg;
            const float gg = rg * (1.f - omf * omf) + (1.f - rg) * (fg * fg);
            const float cn = gg * creg[pp] + (1.f - gg) * ug;
            const float hnv = og * tanhf(cn);
            creg[pp] = cn;
            hn[b * 1024 + ch] = f2bf(hnv);
            out[((size_t)b * 512 + t) * 1024 + ch] = hnv;
            if (t == 511) {
                hcout[b * 1024 + ch] = hnv;            // h_n
                hcout[65536 + b * 1024 + ch] = cn;     // c_n
            }
        }

        // ---- device-wide step barrier (also covers LDS reuse via its block barriers) ----
        grid_barrier(bar, (unsigned int)(t + 1) * gridDim.x);
    }
}

extern "C" void kernel_launch(void* const* d_in, const int* in_sizes, int n_in,
                              void* d_out, int out_size, void* d_ws, size_t ws_size,
                              hipStream_t stream) {
    const float* x   = (const float*)d_in[0];
    const float* wih = (const float*)d_in[1];
    const float* bih = (const float*)d_in[2];
    const float* whh = (const float*)d_in[3];
    const float* bhh = (const float*)d_in[4];
    const float* fb  = (const float*)d_in[5];
    const float* h0  = (const float*)d_in[6];
    const float* c0  = (const float*)d_in[7];

    char* ws = (char*)d_ws;
    float* out = (float*)d_out;
    float* hc  = out + 33554432;  // h_n, then c_n

    unsigned short* xb   = (unsigned short*)(ws + OFF_XB);
    unsigned short* wihb = (unsigned short*)(ws + OFF_WIH);
    unsigned short* whhb = (unsigned short*)(ws + OFF_WHH);
    float* bias          = (float*)(ws + OFF_BIAS);
    unsigned short* hb0  = (unsigned short*)(ws + OFF_H0);
    unsigned short* hb1  = (unsigned short*)(ws + OFF_H1);
    unsigned int* bar    = (unsigned int*)(ws + OFF_BAR);
    void* xw             = (void*)(ws + OFF_XW);

    const bool f32path = ws_size >= OFF_XW + XW_F32_BYTES;

    cast4_kernel<<<32768, 256, 0, stream>>>(x, xb, 8388608);
    cast4_kernel<<<4096, 256, 0, stream>>>(wih, wihb, 1048576);
    cast4_kernel<<<4096, 256, 0, stream>>>(whh, whhb, 1048576);
    init_misc<<<256, 256, 0, stream>>>(bih, bhh, bias, h0, hb0, bar);

    dim3 g(256, 32);
    if (f32path) xw_gemm<true><<<g, 256, 0, stream>>>(xb, wihb, bias, xw);
    else         xw_gemm<false><<<g, 256, 0, stream>>>(xb, wihb, bias, xw);

    const float* fbp = fb;
    const float* c0p = c0;
    void* xwp = xw;
    const unsigned short* whhp = whhb;
    void* kargs[] = { &hb0, &hb1, &xwp, &whhp, &fbp, &c0p, &out, &hc, &bar };
    if (f32path)
        hipLaunchCooperativeKernel((void*)lstm_persistent<true>, dim3(64), dim3(512),
                                   kargs, 0, stream);
    else
        hipLaunchCooperativeKernel((void*)lstm_persistent<false>, dim3(64), dim3(512),
                                   kargs, 0, stream);
}

// Round 3
// 6556.018 us; speedup vs baseline: 2.0265x; 1.8564x over previous
//
#include <hip/hip_runtime.h>
#include <stdint.h>
#include <stddef.h>

typedef __attribute__((ext_vector_type(8))) short short8;
typedef __attribute__((ext_vector_type(4))) float f32x4;

#define MFMA16(A, B, C) __builtin_amdgcn_mfma_f32_16x16x32_bf16((A), (B), (C), 0, 0, 0)

// ---------- workspace layout (bytes) ----------
static const size_t OFF_XB   = 0;                    // x bf16      [64*512, 1024]  67108864
static const size_t OFF_WIH  = 67108864;             // w_ih bf16   [4096, 1024]     8388608
static const size_t OFF_WHH  = 75497472;             // w_hh bf16   [4096, 1024]     8388608
static const size_t OFF_BIAS = 83886080;             // b_ih+b_hh   [4096] f32         16384
static const size_t OFF_H0   = 83902464;             // h buf 0 bf16 [64,1024]        131072
static const size_t OFF_H1   = 84033536;             // h buf 1 bf16                  131072
static const size_t OFF_FLG  = 84164608;             // per-block flags u32[64]
static const size_t OFF_XW   = 84426752;             // xW [512*64, 4096] f32 or bf16
static const size_t XW_F32_BYTES = 536870912;

__device__ __forceinline__ unsigned short f2bf(float f) {
    union { float f; uint32_t u; } v; v.f = f;
    uint32_t u = v.u;
    u += 0x7FFFu + ((u >> 16) & 1u);   // round-to-nearest-even
    return (unsigned short)(u >> 16);
}
__device__ __forceinline__ float bf2f(unsigned short b) {
    union { uint32_t u; float f; } v; v.u = ((uint32_t)b) << 16;
    return v.f;
}

// agent-scope (sc1, L2-bypassing) 16-byte fragment load as 2 x u64 relaxed atomics
__device__ __forceinline__ short8 frag_ld_agent(const unsigned short* p) {
    union { unsigned long long q[2]; short8 s; } u;
    u.q[0] = __hip_atomic_load((const unsigned long long*)p,
                               __ATOMIC_RELAXED, __HIP_MEMORY_SCOPE_AGENT);
    u.q[1] = __hip_atomic_load((const unsigned long long*)(p + 4),
                               __ATOMIC_RELAXED, __HIP_MEMORY_SCOPE_AGENT);
    return u.s;
}

// ---------- cast fp32 -> bf16, 4 elems/thread ----------
__global__ __launch_bounds__(256) void cast4_kernel(const float* __restrict__ s,
                                                    unsigned short* __restrict__ d, int n4) {
    int i = blockIdx.x * 256 + threadIdx.x;
    if (i >= n4) return;
    float4 f = ((const float4*)s)[i];
    ushort4 o;
    o.x = f2bf(f.x); o.y = f2bf(f.y); o.z = f2bf(f.z); o.w = f2bf(f.w);
    ((ushort4*)d)[i] = o;
}

// ---------- bias fold + h0 init + flags zero ----------
__global__ __launch_bounds__(256) void init_misc(const float* __restrict__ b_ih,
                                                 const float* __restrict__ b_hh,
                                                 float* __restrict__ bias,
                                                 const float* __restrict__ h0,
                                                 unsigned short* __restrict__ h_ini,
                                                 unsigned int* __restrict__ flags) {
    int i = blockIdx.x * 256 + threadIdx.x;
    if (i < 64) flags[i] = 0u;
    if (i < 4096) bias[i] = b_ih[i] + b_hh[i];
    if (i < 65536) h_ini[i] = f2bf(h0[i]);
}

// ---------- xW GEMM: C[t*64+b][g] = sum_k x[b*512+t][k] * w_ih[g][k] + bias[g] ----------
template <bool XWF32>
__global__ __launch_bounds__(256) void xw_gemm(const unsigned short* __restrict__ xb,
                                               const unsigned short* __restrict__ wb,
                                               const float* __restrict__ bias,
                                               void* __restrict__ xw) {
    __shared__ __align__(16) unsigned short As[128 * 32];
    __shared__ __align__(16) unsigned short Bs[128 * 32];
    const int bm = blockIdx.x, bn = blockIdx.y;
    const int tid = threadIdx.x;
    const int wave = tid >> 6, lane = tid & 63;
    const int wm = (wave >> 1) * 64, wn = (wave & 1) * 64;
    const int lr = lane & 15, lk = (lane >> 4) * 8;

    const int c0 = tid, c1 = tid + 256;
    const int r0 = c0 >> 2, k0c = (c0 & 3) * 8;
    const int r1 = c1 >> 2, k1c = (c1 & 3) * 8;
    const int mA0 = bm * 128 + r0, mA1 = bm * 128 + r1;
    const unsigned short* pa0 = xb + (size_t)(((mA0 & 63) << 9) + (mA0 >> 6)) * 1024 + k0c;
    const unsigned short* pa1 = xb + (size_t)(((mA1 & 63) << 9) + (mA1 >> 6)) * 1024 + k1c;
    const unsigned short* pb0 = wb + (size_t)(bn * 128 + r0) * 1024 + k0c;
    const unsigned short* pb1 = wb + (size_t)(bn * 128 + r1) * 1024 + k1c;
    unsigned short* sa0 = As + r0 * 32 + k0c;
    unsigned short* sa1 = As + r1 * 32 + k1c;
    unsigned short* sb0 = Bs + r0 * 32 + k0c;
    unsigned short* sb1 = Bs + r1 * 32 + k1c;

    f32x4 acc[4][4] = {};

    for (int kk = 0; kk < 32; ++kk) {
        const int ko = kk * 32;
        uint4 av0 = *(const uint4*)(pa0 + ko);
        uint4 av1 = *(const uint4*)(pa1 + ko);
        uint4 bv0 = *(const uint4*)(pb0 + ko);
        uint4 bv1 = *(const uint4*)(pb1 + ko);
        __syncthreads();
        *(uint4*)sa0 = av0;
        *(uint4*)sa1 = av1;
        *(uint4*)sb0 = bv0;
        *(uint4*)sb1 = bv1;
        __syncthreads();
        short8 af[4], bfr[4];
#pragma unroll
        for (int mi = 0; mi < 4; ++mi)
            af[mi] = *(const short8*)(As + (wm + mi * 16 + lr) * 32 + lk);
#pragma unroll
        for (int ni = 0; ni < 4; ++ni)
            bfr[ni] = *(const short8*)(Bs + (wn + ni * 16 + lr) * 32 + lk);
#pragma unroll
        for (int mi = 0; mi < 4; ++mi)
#pragma unroll
            for (int ni = 0; ni < 4; ++ni)
                acc[mi][ni] = MFMA16(af[mi], bfr[ni], acc[mi][ni]);
    }

    const int rbase = (lane >> 4) * 4;
#pragma unroll
    for (int ni = 0; ni < 4; ++ni) {
        const int gc = bn * 128 + wn + ni * 16 + lr;
        const float bv = bias[gc];
#pragma unroll
        for (int mi = 0; mi < 4; ++mi) {
            const int gr = bm * 128 + wm + mi * 16 + rbase;
#pragma unroll
            for (int r = 0; r < 4; ++r) {
                float v = acc[mi][ni][r] + bv;
                if (XWF32) ((float*)xw)[(size_t)(gr + r) * 4096 + gc] = v;
                else ((unsigned short*)xw)[(size_t)(gr + r) * 4096 + gc] = f2bf(v);
            }
        }
    }
}

// ---------- persistent recurrence: 64 blocks x 512 thr, fence-free dataflow sync ----------
// Block bk owns channels [bk*16, bk*16+16) x 4 gates = 64 rows of w_hh, in REGISTERS
// (pinned via asm keep-alive so the loop's barriers can't force rematerialization).
// All cross-block traffic (h double buffer, flags) uses agent-scope relaxed atomics
// (sc1: bypasses non-coherent per-XCD L2, hits shared L3) -> NO wbl2/inv fences needed.
template <bool XWF32>
__global__ __launch_bounds__(512, 2) void lstm_persistent(
        unsigned short* hb0, unsigned short* hb1,
        const void* __restrict__ xw,
        const unsigned short* __restrict__ whh,
        const float* __restrict__ fb,
        const float* __restrict__ c0,
        float* __restrict__ out,
        float* __restrict__ hcout,
        unsigned int* flags) {
    const int tid = threadIdx.x;
    const int wave = tid >> 6, lane = tid & 63;
    const int bk = blockIdx.x, ch0 = bk * 16;
    const int mh = wave >> 2, kq = wave & 3;
    const int lr = lane & 15, lk = (lane >> 4) * 8, rbase = (lane >> 4) * 4;
    const int kqoff = kq * 256;

    __shared__ float part[4][64][65];   // padded: breaks the 4-way bank conflict

    // ---- preload W_hh fragments into registers (live for all 512 steps) ----
    short8 Bf[4][8];
#pragma unroll
    for (int ni = 0; ni < 4; ++ni) {
        const unsigned short* wrow = whh + (size_t)(ni * 1024 + ch0 + lr) * 1024 + kqoff + lk;
#pragma unroll
        for (int ks = 0; ks < 8; ++ks)
            Bf[ni][ks] = *(const short8*)(wrow + ks * 32);
    }
#pragma unroll
    for (int ni = 0; ni < 4; ++ni)
#pragma unroll
        for (int ks = 0; ks < 8; ++ks)
            asm volatile("" : "+v"(Bf[ni][ks]));   // pin in VGPRs; defeat remat across barriers

    // ---- epilogue map: thread owns (batch b, channel pair ch,ch+1) ----
    const int b  = tid >> 3;
    const int ch = ch0 + 2 * (tid & 7);
    const float fb0 = fb[ch], fb1 = fb[ch + 1];
    float c0r = c0[b * 1024 + ch], c1r = c0[b * 1024 + ch + 1];

    // ---- prefetch xW for t=0 ----
    float xwv[4][2];
    {
        const size_t base = (size_t)b * 4096 + ch;
#pragma unroll
        for (int g = 0; g < 4; ++g) {
            if (XWF32) {
                const float2 v = *(const float2*)((const float*)xw + base + g * 1024);
                xwv[g][0] = v.x; xwv[g][1] = v.y;
            } else {
                const uint32_t u = *(const uint32_t*)((const unsigned short*)xw + base + g * 1024);
                xwv[g][0] = bf2f((unsigned short)u);
                xwv[g][1] = bf2f((unsigned short)(u >> 16));
            }
        }
    }

    for (int t = 0; t < 512; ++t) {
        const unsigned short* hp = (t & 1) ? hb1 : hb0;
        unsigned short* hn       = (t & 1) ? hb0 : hb1;

        // ---- MFMA: lin_partial[b in mh-half][n] over K-quarter kq (h via sc1 loads) ----
        f32x4 acc[2][4] = {};
        const unsigned short* pa0 = hp + (size_t)(mh * 32 + lr) * 1024 + kqoff + lk;
        const unsigned short* pa1 = pa0 + 16 * 1024;
#pragma unroll
        for (int ks = 0; ks < 8; ++ks) {
            short8 a0 = frag_ld_agent(pa0 + ks * 32);
            short8 a1 = frag_ld_agent(pa1 + ks * 32);
#pragma unroll
            for (int ni = 0; ni < 4; ++ni) {
                acc[0][ni] = MFMA16(a0, Bf[ni][ks], acc[0][ni]);
                acc[1][ni] = MFMA16(a1, Bf[ni][ks], acc[1][ni]);
            }
        }

        // ---- write K-partials to LDS ----
#pragma unroll
        for (int mi = 0; mi < 2; ++mi)
#pragma unroll
            for (int ni = 0; ni < 4; ++ni)
#pragma unroll
                for (int r = 0; r < 4; ++r)
                    part[kq][mh * 32 + mi * 16 + rbase + r][ni * 16 + lr] = acc[mi][ni][r];
        __syncthreads();

        // ---- reduce K-partials + gates + state update (2 channels/thread) ----
        {
            const int j0 = 2 * (tid & 7);
            float l0[4], l1[4];
#pragma unroll
            for (int g = 0; g < 4; ++g) {
                float2 s0 = *(const float2*)&part[0][b][g * 16 + j0];
                float2 s1 = *(const float2*)&part[1][b][g * 16 + j0];
                float2 s2 = *(const float2*)&part[2][b][g * 16 + j0];
                float2 s3 = *(const float2*)&part[3][b][g * 16 + j0];
                l0[g] = s0.x + s1.x + s2.x + s3.x + xwv[g][0];
                l1[g] = s0.y + s1.y + s2.y + s3.y + xwv[g][1];
            }
            const float rg0 = 1.f / (1.f + expf(-(l0[0] - fb0)));
            const float fg0 = 1.f / (1.f + expf(-(l0[1] + fb0)));
            const float ug0 = tanhf(l0[2]);
            const float og0 = 1.f / (1.f + expf(-l0[3]));
            const float rg1 = 1.f / (1.f + expf(-(l1[0] - fb1)));
            const float fg1 = 1.f / (1.f + expf(-(l1[1] + fb1)));
            const float ug1 = tanhf(l1[2]);
            const float og1 = 1.f / (1.f + expf(-l1[3]));
            const float of0 = 1.f - fg0, of1 = 1.f - fg1;
            const float gg0 = rg0 * (1.f - of0 * of0) + (1.f - rg0) * (fg0 * fg0);
            const float gg1 = rg1 * (1.f - of1 * of1) + (1.f - rg1) * (fg1 * fg1);
            c0r = gg0 * c0r + (1.f - gg0) * ug0;
            c1r = gg1 * c1r + (1.f - gg1) * ug1;
            const float h0v = og0 * tanhf(c0r);
            const float h1v = og1 * tanhf(c1r);

            // h (cross-block): one u32 agent-scope store -> straight to L3
            const unsigned hw = ((unsigned)f2bf(h1v) << 16) | (unsigned)f2bf(h0v);
            __hip_atomic_store((unsigned int*)&hn[b * 1024 + ch], hw,
                               __ATOMIC_RELAXED, __HIP_MEMORY_SCOPE_AGENT);
            // block-local outputs: plain cached stores
            *(float2*)&out[((size_t)b * 512 + t) * 1024 + ch] = make_float2(h0v, h1v);
            if (t == 511) {
                *(float2*)&hcout[b * 1024 + ch] = make_float2(h0v, h1v);
                *(float2*)&hcout[65536 + b * 1024 + ch] = make_float2(c0r, c1r);
            }
        }

        // ---- prefetch xW for t+1 (independent of h; completes during barrier) ----
        {
            const int tp = (t < 511) ? t + 1 : 511;
            const size_t base = ((size_t)tp * 64 + b) * 4096 + ch;
#pragma unroll
            for (int g = 0; g < 4; ++g) {
                if (XWF32) {
                    const float2 v = *(const float2*)((const float*)xw + base + g * 1024);
                    xwv[g][0] = v.x; xwv[g][1] = v.y;
                } else {
                    const uint32_t u = *(const uint32_t*)((const unsigned short*)xw + base + g * 1024);
                    xwv[g][0] = bf2f((unsigned short)u);
                    xwv[g][1] = bf2f((unsigned short)(u >> 16));
                }
            }
        }

        // ---- fence-free grid barrier: syncthreads drains vmcnt (h stores at L3), then
        //      one flag store per block + read-only poll of 64 flags by wave 0 ----
        __syncthreads();
        if (wave == 0) {
            if (lane == 0)
                __hip_atomic_store(&flags[bk], (unsigned)(t + 1),
                                   __ATOMIC_RELAXED, __HIP_MEMORY_SCOPE_AGENT);
            const unsigned tgt = (unsigned)(t + 1);
            while (!__all((int)(__hip_atomic_load(&flags[lane], __ATOMIC_RELAXED,
                                                  __HIP_MEMORY_SCOPE_AGENT) >= tgt))) {}
        }
        __syncthreads();
    }
}

extern "C" void kernel_launch(void* const* d_in, const int* in_sizes, int n_in,
                              void* d_out, int out_size, void* d_ws, size_t ws_size,
                              hipStream_t stream) {
    const float* x   = (const float*)d_in[0];
    const float* wih = (const float*)d_in[1];
    const float* bih = (const float*)d_in[2];
    const float* whh = (const float*)d_in[3];
    const float* bhh = (const float*)d_in[4];
    const float* fb  = (const float*)d_in[5];
    const float* h0  = (const float*)d_in[6];
    const float* c0  = (const float*)d_in[7];

    char* ws = (char*)d_ws;
    float* out = (float*)d_out;
    float* hc  = out + 33554432;  // h_n, then c_n

    unsigned short* xb   = (unsigned short*)(ws + OFF_XB);
    unsigned short* wihb = (unsigned short*)(ws + OFF_WIH);
    unsigned short* whhb = (unsigned short*)(ws + OFF_WHH);
    float* bias          = (float*)(ws + OFF_BIAS);
    unsigned short* hb0  = (unsigned short*)(ws + OFF_H0);
    unsigned short* hb1  = (unsigned short*)(ws + OFF_H1);
    unsigned int* flags  = (unsigned int*)(ws + OFF_FLG);
    void* xw             = (void*)(ws + OFF_XW);

    const bool f32path = ws_size >= OFF_XW + XW_F32_BYTES;

    cast4_kernel<<<32768, 256, 0, stream>>>(x, xb, 8388608);
    cast4_kernel<<<4096, 256, 0, stream>>>(wih, wihb, 1048576);
    cast4_kernel<<<4096, 256, 0, stream>>>(whh, whhb, 1048576);
    init_misc<<<256, 256, 0, stream>>>(bih, bhh, bias, h0, hb0, flags);

    dim3 g(256, 32);
    if (f32path) xw_gemm<true><<<g, 256, 0, stream>>>(xb, wihb, bias, xw);
    else         xw_gemm<false><<<g, 256, 0, stream>>>(xb, wihb, bias, xw);

    const float* fbp = fb;
    const float* c0p = c0;
    void* xwp = xw;
    const unsigned short* whhp = whhb;
    void* kargs[] = { &hb0, &hb1, &xwp, &whhp, &fbp, &c0p, &out, &hc, &flags };
    if (f32path)
        hipLaunchCooperativeKernel((void*)lstm_persistent<true>, dim3(64), dim3(512),
                                   kargs, 0, stream);
    else
        hipLaunchCooperativeKernel((void*)lstm_persistent<false>, dim3(64), dim3(512),
                                   kargs, 0, stream);
}

// Round 4
// 5635.186 us; speedup vs baseline: 2.3576x; 1.1634x over previous
//
#include <hip/hip_runtime.h>
#include <stdint.h>
#include <stddef.h>

typedef __attribute__((ext_vector_type(8))) short short8;
typedef __attribute__((ext_vector_type(4))) float f32x4;

#define MFMA16(A, B, C) __builtin_amdgcn_mfma_f32_16x16x32_bf16((A), (B), (C), 0, 0, 0)

// ---------- workspace layout (bytes) ----------
static const size_t OFF_XB   = 0;                    // x bf16      [64*512, 1024]  67108864
static const size_t OFF_WIH  = 67108864;             // w_ih bf16   [4096, 1024]     8388608
static const size_t OFF_WHH  = 75497472;             // w_hh bf16   [4096, 1024]     8388608
static const size_t OFF_BIAS = 83886080;             // b_ih+b_hh   [4096] f32         16384
static const size_t OFF_H0   = 83902464;             // h buf 0 bf16 [64,1024]        131072
static const size_t OFF_H1   = 84033536;             // h buf 1 bf16                  131072
static const size_t OFF_FLG  = 84164608;             // per-block flags u32[64]
static const size_t OFF_XW   = 84426752;             // xW [512*64, 4096] f32 or bf16
static const size_t XW_F32_BYTES = 536870912;

__device__ __forceinline__ unsigned short f2bf(float f) {
    union { float f; uint32_t u; } v; v.f = f;
    uint32_t u = v.u;
    u += 0x7FFFu + ((u >> 16) & 1u);   // round-to-nearest-even
    return (unsigned short)(u >> 16);
}
__device__ __forceinline__ float bf2f(unsigned short b) {
    union { uint32_t u; float f; } v; v.u = ((uint32_t)b) << 16;
    return v.f;
}

// agent-scope (sc1, L2-bypassing) 16-byte fragment load as 2 x u64 relaxed atomics
__device__ __forceinline__ short8 frag_ld_agent(const unsigned short* p) {
    union { unsigned long long q[2]; short8 s; } u;
    u.q[0] = __hip_atomic_load((const unsigned long long*)p,
                               __ATOMIC_RELAXED, __HIP_MEMORY_SCOPE_AGENT);
    u.q[1] = __hip_atomic_load((const unsigned long long*)(p + 4),
                               __ATOMIC_RELAXED, __HIP_MEMORY_SCOPE_AGENT);
    return u.s;
}

__device__ __forceinline__ float fast_sigmoid(float x) {
    return 1.f / (1.f + __expf(-x));
}
__device__ __forceinline__ float fast_tanh(float x) {
    // 1 - 2/(e^2x + 1): x->+inf => 1, x->-inf => -1, no NaN
    return 1.f - 2.f / (__expf(2.f * x) + 1.f);
}

// ---------- cast fp32 -> bf16, 4 elems/thread ----------
__global__ __launch_bounds__(256) void cast4_kernel(const float* __restrict__ s,
                                                    unsigned short* __restrict__ d, int n4) {
    int i = blockIdx.x * 256 + threadIdx.x;
    if (i >= n4) return;
    float4 f = ((const float4*)s)[i];
    ushort4 o;
    o.x = f2bf(f.x); o.y = f2bf(f.y); o.z = f2bf(f.z); o.w = f2bf(f.w);
    ((ushort4*)d)[i] = o;
}

// ---------- bias fold + h0 init + flags zero ----------
__global__ __launch_bounds__(256) void init_misc(const float* __restrict__ b_ih,
                                                 const float* __restrict__ b_hh,
                                                 float* __restrict__ bias,
                                                 const float* __restrict__ h0,
                                                 unsigned short* __restrict__ h_ini,
                                                 unsigned int* __restrict__ flags) {
    int i = blockIdx.x * 256 + threadIdx.x;
    if (i < 64) flags[i] = 0u;
    if (i < 4096) bias[i] = b_ih[i] + b_hh[i];
    if (i < 65536) h_ini[i] = f2bf(h0[i]);
}

// ---------- xW GEMM: C[t*64+b][g] = sum_k x[b*512+t][k] * w_ih[g][k] + bias[g] ----------
template <bool XWF32>
__global__ __launch_bounds__(256) void xw_gemm(const unsigned short* __restrict__ xb,
                                               const unsigned short* __restrict__ wb,
                                               const float* __restrict__ bias,
                                               void* __restrict__ xw) {
    __shared__ __align__(16) unsigned short As[128 * 32];
    __shared__ __align__(16) unsigned short Bs[128 * 32];
    const int bm = blockIdx.x, bn = blockIdx.y;
    const int tid = threadIdx.x;
    const int wave = tid >> 6, lane = tid & 63;
    const int wm = (wave >> 1) * 64, wn = (wave & 1) * 64;
    const int lr = lane & 15, lk = (lane >> 4) * 8;

    const int c0 = tid, c1 = tid + 256;
    const int r0 = c0 >> 2, k0c = (c0 & 3) * 8;
    const int r1 = c1 >> 2, k1c = (c1 & 3) * 8;
    const int mA0 = bm * 128 + r0, mA1 = bm * 128 + r1;
    const unsigned short* pa0 = xb + (size_t)(((mA0 & 63) << 9) + (mA0 >> 6)) * 1024 + k0c;
    const unsigned short* pa1 = xb + (size_t)(((mA1 & 63) << 9) + (mA1 >> 6)) * 1024 + k1c;
    const unsigned short* pb0 = wb + (size_t)(bn * 128 + r0) * 1024 + k0c;
    const unsigned short* pb1 = wb + (size_t)(bn * 128 + r1) * 1024 + k1c;
    unsigned short* sa0 = As + r0 * 32 + k0c;
    unsigned short* sa1 = As + r1 * 32 + k1c;
    unsigned short* sb0 = Bs + r0 * 32 + k0c;
    unsigned short* sb1 = Bs + r1 * 32 + k1c;

    f32x4 acc[4][4] = {};

    for (int kk = 0; kk < 32; ++kk) {
        const int ko = kk * 32;
        uint4 av0 = *(const uint4*)(pa0 + ko);
        uint4 av1 = *(const uint4*)(pa1 + ko);
        uint4 bv0 = *(const uint4*)(pb0 + ko);
        uint4 bv1 = *(const uint4*)(pb1 + ko);
        __syncthreads();
        *(uint4*)sa0 = av0;
        *(uint4*)sa1 = av1;
        *(uint4*)sb0 = bv0;
        *(uint4*)sb1 = bv1;
        __syncthreads();
        short8 af[4], bfr[4];
#pragma unroll
        for (int mi = 0; mi < 4; ++mi)
            af[mi] = *(const short8*)(As + (wm + mi * 16 + lr) * 32 + lk);
#pragma unroll
        for (int ni = 0; ni < 4; ++ni)
            bfr[ni] = *(const short8*)(Bs + (wn + ni * 16 + lr) * 32 + lk);
#pragma unroll
        for (int mi = 0; mi < 4; ++mi)
#pragma unroll
            for (int ni = 0; ni < 4; ++ni)
                acc[mi][ni] = MFMA16(af[mi], bfr[ni], acc[mi][ni]);
    }

    const int rbase = (lane >> 4) * 4;
#pragma unroll
    for (int ni = 0; ni < 4; ++ni) {
        const int gc = bn * 128 + wn + ni * 16 + lr;
        const float bv = bias[gc];
#pragma unroll
        for (int mi = 0; mi < 4; ++mi) {
            const int gr = bm * 128 + wm + mi * 16 + rbase;
#pragma unroll
            for (int r = 0; r < 4; ++r) {
                float v = acc[mi][ni][r] + bv;
                if (XWF32) ((float*)xw)[(size_t)(gr + r) * 4096 + gc] = v;
                else ((unsigned short*)xw)[(size_t)(gr + r) * 4096 + gc] = f2bf(v);
            }
        }
    }
}

// ---------- persistent recurrence: 64 blocks x 512 thr ----------
// Block bk owns channels [bk*16, bk*16+16) x 4 gates = 64 rows of w_hh, in LDS (128 KB,
// XOR-swizzled 16B slots -> conflict-free ds_read_b128). Waves: (mh4 = wave>>1: batch
// quarter of 16 rows, kh = wave&1: K-half of 512). Partials: part[2][64 col][64 batch]
// f32, transposed + slot-swizzled (conflict-free b128 writes). LDS total: exactly 160 KB.
// Step tail ordering: h sc1 store -> __syncthreads (drains ONLY tiny h store) -> flag ->
// THEN out/xW HBM traffic (drains in background) -> poll -> raw s_barrier (no waitcnt).
template <bool XWF32>
__global__ __launch_bounds__(512, 2) void lstm_persistent(
        unsigned short* hb0, unsigned short* hb1,
        const void* __restrict__ xw,
        const unsigned short* __restrict__ whh,
        const float* __restrict__ fb,
        const float* __restrict__ c0,
        float* __restrict__ out,
        float* __restrict__ hcout,
        unsigned int* flags) {
    __shared__ __align__(16) unsigned short Wlds[64 * 1024];   // 131072 B
    __shared__ __align__(16) float part[2 * 64 * 64];          //  32768 B

    const int tid = threadIdx.x;
    const int wave = tid >> 6, lane = tid & 63;
    const int bk = blockIdx.x, ch0 = bk * 16;
    const int mh4 = wave >> 1, kh = wave & 1;
    const int lr = lane & 15, g = lane >> 4;

    // ---- stage W_hh into LDS with slot swizzle (row r: 1024 bf16 = 128 16B-slots) ----
#pragma unroll
    for (int i = 0; i < 16; ++i) {
        const int q = tid + i * 512;           // 0..8191 chunk id
        const int r = q >> 7, s = q & 127;
        const int grow = (r >> 4) * 1024 + ch0 + (r & 15);
        uint4 v = *(const uint4*)(whh + (size_t)grow * 1024 + s * 8);
        const int sp = s ^ (r & 7);
        *(uint4*)&Wlds[r * 1024 + sp * 8] = v;
    }

    // ---- per-thread epilogue constants: thread owns (batch b, channels ch, ch+1) ----
    const int b  = tid >> 3;
    const int j0 = 2 * (tid & 7);
    const int ch = ch0 + j0;
    const float fb0 = fb[ch], fb1 = fb[ch + 1];
    float c0r = c0[b * 1024 + ch], c1r = c0[b * 1024 + ch + 1];

    // ---- prefetch xW for t=0 ----
    float xwv[4][2];
#pragma unroll
    for (int g4 = 0; g4 < 4; ++g4) {
        if (XWF32) {
            const float2 v = *(const float2*)((const float*)xw + (size_t)b * 4096 + g4 * 1024 + ch);
            xwv[g4][0] = v.x; xwv[g4][1] = v.y;
        } else {
            const uint32_t u = *(const uint32_t*)((const unsigned short*)xw + (size_t)b * 4096 + g4 * 1024 + ch);
            xwv[g4][0] = bf2f((unsigned short)u);
            xwv[g4][1] = bf2f((unsigned short)(u >> 16));
        }
    }
    __syncthreads();   // W staged

    for (int t = 0; t < 512; ++t) {
        const unsigned short* hp = (t & 1) ? hb1 : hb0;
        unsigned short* hn       = (t & 1) ? hb0 : hb1;

        // ---- A-frags: h rows (mh4*16+lr), K-half kh, via sc1 loads ----
        const unsigned short* hrow = hp + (size_t)(mh4 * 16 + lr) * 1024 + kh * 512 + g * 8;
        short8 af[16];
#pragma unroll
        for (int ks = 0; ks < 16; ++ks)
            af[ks] = frag_ld_agent(hrow + ks * 32);

        // ---- MFMA over K-half: B from swizzled LDS W ----
        f32x4 acc[4] = {};
#pragma unroll
        for (int ks = 0; ks < 16; ++ks) {
            const int sp = (kh * 64 + ks * 4 + g) ^ (lr & 7);
#pragma unroll
            for (int ni = 0; ni < 4; ++ni) {
                short8 bv = *(const short8*)&Wlds[(ni * 16 + lr) * 1024 + sp * 8];
                acc[ni] = MFMA16(af[ks], bv, acc[ni]);
            }
        }

        // ---- partials to LDS: part[kh][col][batch], b128, slot-swizzled ----
#pragma unroll
        for (int ni = 0; ni < 4; ++ni) {
            const int col = ni * 16 + lr;
            const int sl = (mh4 * 4 + g) ^ (col & 7);
            *(f32x4*)&part[kh * 4096 + col * 64 + sl * 4] = acc[ni];
        }
        __syncthreads();   // partials visible

        // ---- reduce + gates + state update (thread -> batch b, channels ch, ch+1) ----
        float h0v, h1v;
        {
            float l0[4], l1[4];
#pragma unroll
            for (int g4 = 0; g4 < 4; ++g4) {
                const int ca = g4 * 16 + j0, cb = ca + 1;
                const int ia = ((b >> 2) ^ (ca & 7)) * 4 + (b & 3);
                const int ib = ((b >> 2) ^ (cb & 7)) * 4 + (b & 3);
                l0[g4] = part[ca * 64 + ia] + part[4096 + ca * 64 + ia] + xwv[g4][0];
                l1[g4] = part[cb * 64 + ib] + part[4096 + cb * 64 + ib] + xwv[g4][1];
            }
            const float rg0 = fast_sigmoid(l0[0] - fb0);
            const float fg0 = fast_sigmoid(l0[1] + fb0);
            const float ug0 = fast_tanh(l0[2]);
            const float og0 = fast_sigmoid(l0[3]);
            const float rg1 = fast_sigmoid(l1[0] - fb1);
            const float fg1 = fast_sigmoid(l1[1] + fb1);
            const float ug1 = fast_tanh(l1[2]);
            const float og1 = fast_sigmoid(l1[3]);
            const float of0 = 1.f - fg0, of1 = 1.f - fg1;
            const float gg0 = rg0 * (1.f - of0 * of0) + (1.f - rg0) * (fg0 * fg0);
            const float gg1 = rg1 * (1.f - of1 * of1) + (1.f - rg1) * (fg1 * fg1);
            c0r = gg0 * c0r + (1.f - gg0) * ug0;
            c1r = gg1 * c1r + (1.f - gg1) * ug1;
            h0v = og0 * fast_tanh(c0r);
            h1v = og1 * fast_tanh(c1r);

            // h (cross-block): one u32 agent-scope store -> straight to L3
            const unsigned hw = ((unsigned)f2bf(h1v) << 16) | (unsigned)f2bf(h0v);
            __hip_atomic_store((unsigned int*)&hn[b * 1024 + ch], hw,
                               __ATOMIC_RELAXED, __HIP_MEMORY_SCOPE_AGENT);
        }

        // ---- drain h store (tiny) + block barrier, then signal ----
        __syncthreads();   // s_waitcnt vmcnt(0): only h store + long-retired leftovers
        if (tid == 0)
            __hip_atomic_store(&flags[bk], (unsigned)(t + 1),
                               __ATOMIC_RELAXED, __HIP_MEMORY_SCOPE_AGENT);
        __builtin_amdgcn_sched_barrier(0);   // keep HBM traffic BELOW the flag

        // ---- post-flag: HBM traffic drains in background ----
        *(float2*)&out[((size_t)b * 512 + t) * 1024 + ch] = make_float2(h0v, h1v);
        if (t == 511) {
            *(float2*)&hcout[b * 1024 + ch] = make_float2(h0v, h1v);
            *(float2*)&hcout[65536 + b * 1024 + ch] = make_float2(c0r, c1r);
        }
        {
            const int tp = (t < 511) ? t + 1 : 511;
            const size_t base = ((size_t)tp * 64 + b) * 4096 + ch;
#pragma unroll
            for (int g4 = 0; g4 < 4; ++g4) {
                if (XWF32) {
                    const float2 v = *(const float2*)((const float*)xw + base + g4 * 1024);
                    xwv[g4][0] = v.x; xwv[g4][1] = v.y;
                } else {
                    const uint32_t u = *(const uint32_t*)((const unsigned short*)xw + base + g4 * 1024);
                    xwv[g4][0] = bf2f((unsigned short)u);
                    xwv[g4][1] = bf2f((unsigned short)(u >> 16));
                }
            }
        }

        // ---- wave0 polls all 64 flags; raw barrier releases block (NO vmcnt drain) ----
        if (wave == 0) {
            const unsigned tgt = (unsigned)(t + 1);
            while (!__all((int)(__hip_atomic_load(&flags[lane], __ATOMIC_RELAXED,
                                                  __HIP_MEMORY_SCOPE_AGENT) >= tgt))) {}
        }
        __builtin_amdgcn_sched_barrier(0);
        __builtin_amdgcn_s_barrier();
    }
}

extern "C" void kernel_launch(void* const* d_in, const int* in_sizes, int n_in,
                              void* d_out, int out_size, void* d_ws, size_t ws_size,
                              hipStream_t stream) {
    const float* x   = (const float*)d_in[0];
    const float* wih = (const float*)d_in[1];
    const float* bih = (const float*)d_in[2];
    const float* whh = (const float*)d_in[3];
    const float* bhh = (const float*)d_in[4];
    const float* fb  = (const float*)d_in[5];
    const float* h0  = (const float*)d_in[6];
    const float* c0  = (const float*)d_in[7];

    char* ws = (char*)d_ws;
    float* out = (float*)d_out;
    float* hc  = out + 33554432;  // h_n, then c_n

    unsigned short* xb   = (unsigned short*)(ws + OFF_XB);
    unsigned short* wihb = (unsigned short*)(ws + OFF_WIH);
    unsigned short* whhb = (unsigned short*)(ws + OFF_WHH);
    float* bias          = (float*)(ws + OFF_BIAS);
    unsigned short* hb0  = (unsigned short*)(ws + OFF_H0);
    unsigned short* hb1  = (unsigned short*)(ws + OFF_H1);
    unsigned int* flags  = (unsigned int*)(ws + OFF_FLG);
    void* xw             = (void*)(ws + OFF_XW);

    const bool f32path = ws_size >= OFF_XW + XW_F32_BYTES;

    cast4_kernel<<<32768, 256, 0, stream>>>(x, xb, 8388608);
    cast4_kernel<<<4096, 256, 0, stream>>>(wih, wihb, 1048576);
    cast4_kernel<<<4096, 256, 0, stream>>>(whh, whhb, 1048576);
    init_misc<<<256, 256, 0, stream>>>(bih, bhh, bias, h0, hb0, flags);

    dim3 g(256, 32);
    if (f32path) xw_gemm<true><<<g, 256, 0, stream>>>(xb, wihb, bias, xw);
    else         xw_gemm<false><<<g, 256, 0, stream>>>(xb, wihb, bias, xw);

    const float* fbp = fb;
    const float* c0p = c0;
    void* xwp = xw;
    const unsigned short* whhp = whhb;
    void* kargs[] = { &hb0, &hb1, &xwp, &whhp, &fbp, &c0p, &out, &hc, &flags };
    if (f32path)
        hipLaunchCooperativeKernel((void*)lstm_persistent<true>, dim3(64), dim3(512),
                                   kargs, 0, stream);
    else
        hipLaunchCooperativeKernel((void*)lstm_persistent<false>, dim3(64), dim3(512),
                                   kargs, 0, stream);
}